// Round 1
// 663.080 us; speedup vs baseline: 1.0729x; 1.0729x over previous
//
#include <hip/hip_runtime.h>
#include <math.h>

// Problem constants (from reference setup_inputs)
#define B   64      // batch
#define P   64      // pool_size
#define L   5       // prompt_len
#define D   768     // embed_dim
#define K   5       // topk
#define S   2048    // seq_len
#define SOUT (K*L + S)   // 2073 output seq
#define EPS 1e-12f

#define COPY_CHUNKS 384                      // copy blocks per batch
#define NV_PER_CHUNK (S*D/4/COPY_CHUNKS)     // 1024 float4 per block

// ---------------- Kernel 1: fused norms + sim + top-5 + loss-term.
// One block (256 thr = 4 waves) per batch row b.
//  - stage cls[b] in LDS, block-reduce its squared norm
//  - wave w computes pool rows [w*16, w*16+16): per row, 64 lanes read
//    contiguous 64-float chunks of key (coalesced), accumulating BOTH
//    dot(q,k) and sum(k^2); shuffle-reduce both at once
//  - sim[p] = dot * rsqrt(max(ksq,eps)) * rinv_q   (into LDS)
//  - wave 0: 5 rounds of wave-wide argmax (ties -> lowest index)
//  - loss term for this b is exactly sim[b] (p==b): write to ws
// ----------------
__global__ __launch_bounds__(256) void prep_kernel(const float* __restrict__ key,
                                                   const float* __restrict__ cls,
                                                   int* __restrict__ idx_out,
                                                   float* __restrict__ loss_terms) {
    const int b    = blockIdx.x;    // 0..63
    const int t    = threadIdx.x;   // 0..255
    const int lane = t & 63;
    const int wave = t >> 6;

    __shared__ float q_lds[D];
    __shared__ float sim_lds[P];
    __shared__ float red[4];

    // stage query row + partial squared norm
    float qsq = 0.f;
    for (int i = t; i < D; i += 256) {
        float v = cls[(size_t)b * D + i];
        q_lds[i] = v;
        qsq += v * v;
    }
    for (int off = 32; off > 0; off >>= 1) qsq += __shfl_down(qsq, off);
    if (lane == 0) red[wave] = qsq;
    __syncthreads();
    const float rinv_q = rsqrtf(fmaxf(red[0] + red[1] + red[2] + red[3], EPS));

    // each wave: 16 pool rows, coalesced reads, fused dot + key-norm
    for (int r = 0; r < 16; ++r) {
        const int p = wave * 16 + r;
        const float* __restrict__ kr = key + (size_t)p * D;
        float dot = 0.f, ksq = 0.f;
        #pragma unroll
        for (int j = 0; j < D / 64; ++j) {
            float kd = kr[j * 64 + lane];
            float qd = q_lds[j * 64 + lane];
            dot += kd * qd;
            ksq += kd * kd;
        }
        for (int off = 32; off > 0; off >>= 1) {
            dot += __shfl_down(dot, off);
            ksq += __shfl_down(ksq, off);
        }
        if (lane == 0)
            sim_lds[p] = dot * rsqrtf(fmaxf(ksq, EPS)) * rinv_q;
    }
    __syncthreads();

    // loss term: diagonal element sim[b][b]
    if (t == 0) loss_terms[b] = sim_lds[b];

    // wave 0: top-5 argmax rounds (ties -> lowest index, matches lax.top_k)
    if (wave == 0) {
        float sim = sim_lds[lane];
        for (int kk = 0; kk < K; ++kk) {
            float v  = sim;
            int   id = lane;
            for (int off = 32; off > 0; off >>= 1) {
                float ov = __shfl_down(v, off);
                int   oi = __shfl_down(id, off);
                if (ov > v || (ov == v && oi < id)) { v = ov; id = oi; }
            }
            int win = __shfl(id, 0);
            if (lane == 0) idx_out[b * K + kk] = win;
            if (lane == win) sim = -INFINITY;
        }
    }
}

// ---------------- Kernel 2: fused loss-finalize + gather + bulk copy.
// block 0            : reduce 64 loss terms -> out_loss
// blocks 1..B*K      : gather prompt[idx[b][kk]] -> out[b, kk*L:(kk+1)*L, :]
// remaining blocks   : streaming copy x_embed -> out[:, K*L:, :]
// All branches are block-uniform; all accesses float4-aligned/coalesced.
// ----------------
__global__ __launch_bounds__(256) void write_kernel(const float* __restrict__ x,
                                                    const float* __restrict__ prompt,
                                                    const int* __restrict__ idx,
                                                    const float* __restrict__ loss_terms,
                                                    float* __restrict__ out,
                                                    float* __restrict__ out_loss) {
    const int bid = blockIdx.x;
    const int t   = threadIdx.x;

    if (bid == 0) {
        if (t < 64) {
            float s = loss_terms[t];
            for (int off = 32; off > 0; off >>= 1) s += __shfl_down(s, off);
            if (t == 0) *out_loss = s / (float)B;
        }
        return;
    }

    if (bid <= B * K) {                       // gather region
        const int g  = bid - 1;
        const int b  = g / K;
        const int kk = g % K;
        const int pi = idx[g];
        const float4* __restrict__ src = (const float4*)(prompt + (size_t)pi * L * D);
        float4* __restrict__ dst = (float4*)(out + (size_t)b * SOUT * D + (size_t)kk * L * D);
        for (int i = t; i < L * D / 4; i += 256) dst[i] = src[i];
        return;
    }

    // bulk copy region
    const int cb = bid - 1 - B * K;
    const int b  = cb / COPY_CHUNKS;
    const int c  = cb % COPY_CHUNKS;
    const float4* __restrict__ src =
        (const float4*)(x + (size_t)b * S * D) + (size_t)c * NV_PER_CHUNK;
    float4* __restrict__ dst =
        (float4*)(out + (size_t)b * SOUT * D + (size_t)(K * L) * D) + (size_t)c * NV_PER_CHUNK;
    #pragma unroll
    for (int k = 0; k < NV_PER_CHUNK / 256; ++k)
        dst[t + k * 256] = src[t + k * 256];
}

extern "C" void kernel_launch(void* const* d_in, const int* in_sizes, int n_in,
                              void* d_out, int out_size, void* d_ws, size_t ws_size,
                              hipStream_t stream) {
    const float* x_embed    = (const float*)d_in[0];   // (B, S, D)
    const float* cls        = (const float*)d_in[1];   // (B, D)
    const float* prompt     = (const float*)d_in[2];   // (P, L, D)
    const float* prompt_key = (const float*)d_in[3];   // (P, D)
    float* out = (float*)d_out;                        // res (B*SOUT*D) then loss (1)

    // workspace layout: loss_terms[64] floats, then idx[B*K] ints
    float* loss_terms = (float*)d_ws;
    int*   idx        = (int*)((char*)d_ws + 64 * sizeof(float));

    const size_t res_elems = (size_t)B * SOUT * D;     // 101,892,096
    float* out_loss = out + res_elems;

    prep_kernel<<<dim3(B), dim3(256), 0, stream>>>(prompt_key, cls, idx, loss_terms);

    const int nblocks = 1 + B * K + B * COPY_CHUNKS;   // 1 + 320 + 24576 = 24897
    write_kernel<<<dim3(nblocks), dim3(256), 0, stream>>>(
        x_embed, prompt, idx, loss_terms, out, out_loss);
}

// Round 3
// 645.110 us; speedup vs baseline: 1.1028x; 1.0279x over previous
//
#include <hip/hip_runtime.h>
#include <math.h>

// Problem constants (from reference setup_inputs)
#define B   64      // batch
#define P   64      // pool_size
#define L   5       // prompt_len
#define D   768     // embed_dim
#define K   5       // topk
#define S   2048    // seq_len
#define SOUT (K*L + S)   // 2073 output seq
#define EPS 1e-12f

#define COPY_CHUNKS 384                      // copy blocks per batch
#define NV_PER_CHUNK (S*D/4/COPY_CHUNKS)     // 1024 float4 per block

// ---------------- Single fused kernel.
// block 0          : loss = sum_b dot_norm(key[b], cls[b]) / B
// blocks 1..B      : per-batch sim row + top-5 + gather of 5 prompts
//                    (recomputes sim locally -> no cross-kernel dependency)
// blocks B+1..     : streaming copy x_embed -> out[:, K*L:, :]
// Gather/loss blocks are FIRST in the grid so their latency-bound compute
// overlaps with the HBM-bound bulk copy running on the other CUs.
// ----------------
__global__ __launch_bounds__(256) void fused_kernel(
        const float* __restrict__ x,
        const float* __restrict__ cls,
        const float* __restrict__ prompt,
        const float* __restrict__ key,
        float* __restrict__ out,
        float* __restrict__ out_loss) {
    const int bid  = blockIdx.x;
    const int t    = threadIdx.x;   // 0..255
    const int lane = t & 63;
    const int wave = t >> 6;

    if (bid == 0) {
        // ---- loss: sum of normalized diagonal dots ----
        __shared__ float red[4];
        float part = 0.f;
        for (int r = 0; r < 16; ++r) {
            const int b = wave * 16 + r;
            const float* __restrict__ kr = key + (size_t)b * D;
            const float* __restrict__ qr = cls + (size_t)b * D;
            float dot = 0.f, ksq = 0.f, qsq = 0.f;
            #pragma unroll
            for (int j = 0; j < D / 64; ++j) {
                float kd = kr[j * 64 + lane];
                float qd = qr[j * 64 + lane];
                dot += kd * qd; ksq += kd * kd; qsq += qd * qd;
            }
            for (int off = 32; off > 0; off >>= 1) {
                dot += __shfl_down(dot, off);
                ksq += __shfl_down(ksq, off);
                qsq += __shfl_down(qsq, off);
            }
            if (lane == 0)
                part += dot * rsqrtf(fmaxf(ksq, EPS)) * rsqrtf(fmaxf(qsq, EPS));
        }
        if (lane == 0) red[wave] = part;
        __syncthreads();
        if (t == 0) *out_loss = (red[0] + red[1] + red[2] + red[3]) / (float)B;
        return;
    }

    if (bid <= B) {
        // ---- per-batch: sim row + top-5 + gather ----
        const int b = bid - 1;
        __shared__ float q_lds[D];
        __shared__ float sim_lds[P];
        __shared__ float redq[4];
        __shared__ int   win5[K];

        // stage query row + squared norm
        float qsq = 0.f;
        for (int i = t; i < D; i += 256) {
            float v = cls[(size_t)b * D + i];
            q_lds[i] = v;
            qsq += v * v;
        }
        for (int off = 32; off > 0; off >>= 1) qsq += __shfl_down(qsq, off);
        if (lane == 0) redq[wave] = qsq;
        __syncthreads();
        const float rinv_q = rsqrtf(fmaxf(redq[0] + redq[1] + redq[2] + redq[3], EPS));

        // each wave: 16 pool rows, coalesced, fused dot + key-norm
        for (int r = 0; r < 16; ++r) {
            const int p = wave * 16 + r;
            const float* __restrict__ kr = key + (size_t)p * D;
            float dot = 0.f, ksq = 0.f;
            #pragma unroll
            for (int j = 0; j < D / 64; ++j) {
                float kd = kr[j * 64 + lane];
                float qd = q_lds[j * 64 + lane];
                dot += kd * qd;
                ksq += kd * kd;
            }
            for (int off = 32; off > 0; off >>= 1) {
                dot += __shfl_down(dot, off);
                ksq += __shfl_down(ksq, off);
            }
            if (lane == 0)
                sim_lds[p] = dot * rsqrtf(fmaxf(ksq, EPS)) * rinv_q;
        }
        __syncthreads();

        // wave 0: top-5 argmax rounds (ties -> lowest index, matches lax.top_k)
        if (wave == 0) {
            float sim = sim_lds[lane];
            for (int kk = 0; kk < K; ++kk) {
                float v  = sim;
                int   id = lane;
                for (int off = 32; off > 0; off >>= 1) {
                    float ov = __shfl_down(v, off);
                    int   oi = __shfl_down(id, off);
                    if (ov > v || (ov == v && oi < id)) { v = ov; id = oi; }
                }
                int win = __shfl(id, 0);
                if (lane == 0) win5[kk] = win;
                if (lane == win) sim = -INFINITY;
            }
        }
        __syncthreads();

        // gather the 5 selected prompts into the output head
        float4* __restrict__ dstb = (float4*)(out + (size_t)b * SOUT * D);
        #pragma unroll
        for (int kk = 0; kk < K; ++kk) {
            const float4* __restrict__ src =
                (const float4*)(prompt + (size_t)win5[kk] * L * D);
            float4* __restrict__ dst = dstb + kk * (L * D / 4);
            for (int i = t; i < L * D / 4; i += 256) dst[i] = src[i];
        }
        return;
    }

    // ---- bulk copy region ----
    const int cb = bid - 1 - B;
    const int b  = cb / COPY_CHUNKS;
    const int c  = cb % COPY_CHUNKS;
    const float4* __restrict__ src =
        (const float4*)(x + (size_t)b * S * D) + (size_t)c * NV_PER_CHUNK;
    float4* __restrict__ dst =
        (float4*)(out + (size_t)b * SOUT * D + (size_t)(K * L) * D) + (size_t)c * NV_PER_CHUNK;
    #pragma unroll
    for (int k = 0; k < NV_PER_CHUNK / 256; ++k)
        dst[t + k * 256] = src[t + k * 256];
}

extern "C" void kernel_launch(void* const* d_in, const int* in_sizes, int n_in,
                              void* d_out, int out_size, void* d_ws, size_t ws_size,
                              hipStream_t stream) {
    const float* x_embed    = (const float*)d_in[0];   // (B, S, D)
    const float* cls        = (const float*)d_in[1];   // (B, D)
    const float* prompt     = (const float*)d_in[2];   // (P, L, D)
    const float* prompt_key = (const float*)d_in[3];   // (P, D)
    float* out = (float*)d_out;                        // res (B*SOUT*D) then loss (1)

    const size_t res_elems = (size_t)B * SOUT * D;     // 101,892,096
    float* out_loss = out + res_elems;

    const int nblocks = 1 + B + B * COPY_CHUNKS;       // 1 + 64 + 24576 = 24641
    fused_kernel<<<dim3(nblocks), dim3(256), 0, stream>>>(
        x_embed, cls, prompt, prompt_key, out, out_loss);
}